// Round 4
// baseline (453.651 us; speedup 1.0000x reference)
//
#include <hip/hip_runtime.h>

// QRegulariser: theta = hidden[B,H] @ W[Q,H]^T + b;  out = mean(1 - prod_q cos^2(theta_q/2))
// B=65536, H=1024, Q=8.  HBM-bound: stream 256 MB of hidden once (41 us floor).
//
// R3 design: copy-style sequential streaming, zero LDS, zero scalar loads in
// the hot loop.  A wave owns 16 consecutive rows and reads them front-to-back:
// each global_load_dwordx4 is 1 KB fully contiguous (lane L takes floats
// 4L..4L+3 of a quarter-row) -- the same access shape as the 6.6 TB/s fill
// kernel.  Lane L's W operands are therefore the FIXED set
// W[q][i*256+4L .. +3] (q<8, i<4) = 128 floats, preloaded to VGPRs once.
// Hot loop = VMEM(x) + VALU(FMA) only; per-row theta via 6-step shfl_xor
// butterfly (all lanes end uniform); one atomicAdd per wave.

#define HDIM 1024
#define QN 8
#define RPW 16   // rows per wave; 4096 waves total = 1024 blocks x 4 waves

__global__ __launch_bounds__(256, 2)
void qreg_kernel(const float* __restrict__ hidden,
                 const float* __restrict__ W,
                 const float* __restrict__ bias,
                 float* __restrict__ out) {
    const int tid  = threadIdx.x;
    const int lane = tid & 63;
    const int wave = blockIdx.x * 4 + (tid >> 6);
    const size_t row0 = (size_t)wave * RPW;

    // ---- prologue: W fragments -> VGPRs (fixed per lane for the whole kernel)
    float4 wf[QN][4];
#pragma unroll
    for (int q = 0; q < QN; ++q)
#pragma unroll
        for (int i = 0; i < 4; ++i)
            wf[q][i] = *reinterpret_cast<const float4*>(W + q * HDIM + i * 256 + lane * 4);

    float bi[QN];
#pragma unroll
    for (int q = 0; q < QN; ++q) bi[q] = bias[q];

    const float* rp = hidden + row0 * HDIM + lane * 4;

    // pipeline: depth-2 row prefetch, rotating buffers (full unroll -> regs)
    float4 xbuf[3][4];
#pragma unroll
    for (int i = 0; i < 4; ++i) {
        xbuf[0][i] = *reinterpret_cast<const float4*>(rp + 0 * HDIM + i * 256);
        xbuf[1][i] = *reinterpret_cast<const float4*>(rp + 1 * HDIM + i * 256);
    }

    float bsum = 0.f;

#pragma unroll
    for (int r = 0; r < RPW; ++r) {
        const int cur = r % 3;
        // prefetch row r+2
        if (r + 2 < RPW) {
            const int nxt = (r + 2) % 3;
#pragma unroll
            for (int i = 0; i < 4; ++i)
                xbuf[nxt][i] = *reinterpret_cast<const float4*>(rp + (size_t)(r + 2) * HDIM + i * 256);
        }

        // per-lane partial dot for all 8 qubits (pure VALU, W in regs)
        float t[QN];
#pragma unroll
        for (int q = 0; q < QN; ++q) {
            float a = 0.f;
#pragma unroll
            for (int i = 0; i < 4; ++i) {
                a += xbuf[cur][i].x * wf[q][i].x + xbuf[cur][i].y * wf[q][i].y
                   + xbuf[cur][i].z * wf[q][i].z + xbuf[cur][i].w * wf[q][i].w;
            }
            t[q] = a;
        }

        // 64-lane butterfly reduce per q -> all lanes hold full theta
#pragma unroll
        for (int off = 1; off < 64; off <<= 1)
#pragma unroll
            for (int q = 0; q < QN; ++q)
                t[q] += __shfl_xor(t[q], off, 64);

        float p0 = 1.f;
#pragma unroll
        for (int q = 0; q < QN; ++q) {
            float c = __cosf(0.5f * (t[q] + bi[q]));
            p0 *= c * c;
        }
        bsum += 1.f - p0;
    }

    if (lane == 0)
        atomicAdd(out, bsum * (1.0f / 65536.0f));
}

extern "C" void kernel_launch(void* const* d_in, const int* in_sizes, int n_in,
                              void* d_out, int out_size, void* d_ws, size_t ws_size,
                              hipStream_t stream) {
    const float* hidden = (const float*)d_in[0];
    const float* W      = (const float*)d_in[1];
    const float* bias   = (const float*)d_in[2];
    float* out          = (float*)d_out;

    hipMemsetAsync(out, 0, sizeof(float), stream);
    qreg_kernel<<<1024, 256, 0, stream>>>(hidden, W, bias, out);
}